// Round 9
// baseline (498.730 us; speedup 1.0000x reference)
//
#include <hip/hip_runtime.h>

#define N_  8
#define C_  32
#define H_  224
#define W_  224
#define TM_ 4

// R9: ZERO-BARRIER kernel. Block = 256 threads = 4 INDEPENDENT waves, one per
// t (wave w owns output channel c*4+w). A single wave can do the LDS transpose
// alone: DS ops of one wave complete in order, so ds_write -> lgkmcnt(0) ->
// ds_read needs NO s_barrier. Four structurally different barrier schedules
// (R1/R6/R8) all pinned at ~150us with nothing saturated -> the lockstep
// block was the bottleneck, not occupancy/MLP/traffic.
// Bonus: the 4 t-waves of a block gather the SAME ~6KB input window
// concurrently on one CU -> t-reuse through L1 (R1 refetched it 4x from HBM),
// with zero temporal distance (R5's cross-time reuse trap doesn't apply).
// Per wave: 2 ph-halves x 8 b-cols; per n: 32 gathers (prefetched one n ahead,
// issued BEFORE the compiler clobber so they stay in flight across the LDS
// round trip) -> FMA -> ds_write [a][col] -> lgkmcnt(0) -> transposed float4
// stores. LDS slice [2][32][17]: stride 17 = conflict-free writes, 2-way reads
// (free). Double buffer so ds_writes(n+1) can overlap reads(n).
// Reference quirk preserved: hx = xs[a], hy = ys[b]; out channel = c*TM + t.
__global__ __launch_bounds__(256, 4) void persp_kernel(
    const float* __restrict__ inp,   // (N, C, H, W)
    const float* __restrict__ wt,    // (TM, C, 8)
    float* __restrict__ out)         // (N, C*TM, H, W)
{
    __shared__ float lds[TM_][2][32][17];   // 17408 B, one slice per wave

    const int tid   = threadIdx.x;
    const int t     = tid >> 6;        // wave id == warp index == t
    const int lane  = tid & 63;
    const int a_off = lane & 31;       // gather phase: lane -> a
    const int half  = lane >> 5;       // 0,1 -> b parity group

    const int c  = blockIdx.y;
    const int ta = blockIdx.x / 7;
    const int tb = blockIdx.x % 7;
    const int a0 = ta * 32;
    const int b0 = tb * 32;

    const float step = 2.0f / 223.0f;                    // linspace(-1,1,224)
    const float hx   = -1.0f + (float)(a0 + a_off) * step;   // xs[a]

    // transposed-read phase: lane -> (row rrow+16k, 4 consecutive cols rcol)
    const int rrow = lane >> 2;        // 0..15
    const int rcol = (lane & 3) * 4;   // 0,4,8,12

    const size_t plane   = (size_t)H_ * W_;
    const size_t istride = (size_t)C_ * plane;
    const size_t ostride = (size_t)(C_ * TM_) * plane;

    const float* th = wt + ((size_t)t * C_ + c) * 8;
    const float t0 = th[0], t1 = th[1], t2 = th[2], t3 = th[3];
    const float t4 = th[4], t5 = th[5], t6 = th[6], t7 = th[7];

    const float* ibc = inp + (size_t)c * plane;
    float* oc = out + (size_t)(c * TM_ + t) * plane;

    for (int ph = 0; ph < 2; ++ph) {
        // ---- geometry for this wave's 16 b-columns (8 per lane-half) ----
        int   iA[8], iB[8], dx[8];
        float wa_[8], wb_[8], wc_[8], wd_[8];
#pragma unroll
        for (int p = 0; p < 8; ++p) {
            const int b = b0 + half + 2 * (ph * 8 + p);
            const float hy = -1.0f + (float)b * step;    // ys[b]

            const float w0 = t0 * hx + t1 * hy + t2;
            const float w1 = t3 * hx + t4 * hy + t5;
            const float w2 = t6 * hx + t7 * hy + 1.0f;

            const float xs = w0 / w2;
            const float ys = w1 / w2;

            const float x = 0.5f * ((xs + 1.0f) * 222.0f);
            const float y = 0.5f * ((ys + 1.0f) * 222.0f);

            int x0i = (int)floorf(x);
            int y0i = (int)floorf(y);
            int x1i = x0i + 1;
            int y1i = y0i + 1;
            x0i = min(max(x0i, 0), W_ - 1);
            x1i = min(max(x1i, 0), W_ - 1);
            y0i = min(max(y0i, 0), H_ - 1);
            y1i = min(max(y1i, 0), H_ - 1);

            const float x0f = (float)x0i, x1f = (float)x1i;
            const float y0f = (float)y0i, y1f = (float)y1i;

            wa_[p] = (x1f - x) * (y1f - y);
            wb_[p] = (x1f - x) * (y1f - y0f);
            wc_[p] = (x - x0f) * (y1f - y);
            wd_[p] = (x - x0f) * (y - y0f);

            iA[p] = y0i * W_ + x0i;          // C-tap = iA + dx
            iB[p] = y1i * W_ + x0i;          // D-tap = iB + dx
            dx[p] = x1i - x0i;               // 1 interior, 0 at x-clamp
        }

        // ---- pipelined n loop: gathers one n ahead, no barriers ----
        float gA[8], gB[8], gC[8], gD[8];
#pragma unroll
        for (int p = 0; p < 8; ++p) {        // preload n = 0
            gA[p] = ibc[iA[p]];
            gC[p] = ibc[iA[p] + dx[p]];
            gB[p] = ibc[iB[p]];
            gD[p] = ibc[iB[p] + dx[p]];
        }

#pragma unroll
        for (int n = 0; n < N_; ++n) {
            // consume current gathers -> LDS (ds_writes counted by lgkmcnt)
#pragma unroll
            for (int p = 0; p < 8; ++p)
                lds[t][n & 1][a_off][half + 2 * p] =
                    wa_[p] * gA[p] + wb_[p] * gB[p] +
                    wc_[p] * gC[p] + wd_[p] * gD[p];

            // prefetch next n BEFORE the clobber -> stays in flight across
            // the LDS round trip and stores
            if (n < N_ - 1) {
                const float* ib = ibc + (size_t)(n + 1) * istride;
#pragma unroll
                for (int p = 0; p < 8; ++p) {
                    gA[p] = ib[iA[p]];
                    gC[p] = ib[iA[p] + dx[p]];
                    gB[p] = ib[iB[p]];
                    gD[p] = ib[iB[p] + dx[p]];
                }
            }

            // drain this wave's ds_writes only (no barrier, no vmcnt drain)
            asm volatile("s_waitcnt lgkmcnt(0)" ::: "memory");

            // transposed read + coalesced float4 stores
            float* on = oc + (size_t)n * ostride + (size_t)a0 * W_
                           + (b0 + 16 * ph);
#pragma unroll
            for (int k = 0; k < 2; ++k) {
                const int i = rrow + 16 * k;
                float4 v;
                v.x = lds[t][n & 1][i][rcol + 0];
                v.y = lds[t][n & 1][i][rcol + 1];
                v.z = lds[t][n & 1][i][rcol + 2];
                v.w = lds[t][n & 1][i][rcol + 3];
                *reinterpret_cast<float4*>(on + (size_t)i * W_ + rcol) = v;
            }
        }
    }
}

extern "C" void kernel_launch(void* const* d_in, const int* in_sizes, int n_in,
                              void* d_out, int out_size, void* d_ws, size_t ws_size,
                              hipStream_t stream) {
    const float* inp = (const float*)d_in[0];   // (8,32,224,224) f32
    const float* wt  = (const float*)d_in[1];   // (4,32,8) f32
    float* out = (float*)d_out;                 // (8,128,224,224) f32

    dim3 grid(7 * 7, C_);                       // 49 x 32 = 1568 blocks
    persp_kernel<<<grid, 256, 0, stream>>>(inp, wt, out);
}